// Round 1
// 549.385 us; speedup vs baseline: 1.0779x; 1.0779x over previous
//
#include <hip/hip_runtime.h>
#include <math.h>

// Problem constants (B=2, H=8, S=2048, D=64)
#define BH_    16          // B*H
#define S_     2048
#define D_     64
#define QT     4           // queries per block
#define BLOCK  256
#define KPT    8           // keys per thread in phase 1 = S_/BLOCK
#define NEWTON_ITERS 16

__device__ __forceinline__ float comp(const float4& a, int u) {
  return u == 0 ? a.x : u == 1 ? a.y : u == 2 ? a.z : a.w;
}

// __launch_bounds__(256,4): cap VGPR ~128 so 4 waves/SIMD co-reside.
// R1 evidence: without it VGPR=256 + 265MB spill traffic, occupancy 12%.
__global__ __launch_bounds__(BLOCK, 4)
void entmax_attn_kernel(const float* __restrict__ q,
                        const float* __restrict__ k,
                        const float* __restrict__ v,
                        float* __restrict__ out) {
  // sc: scores -> p -> (aliased) phase-4 partial sums. 32KB.
  __shared__ float sc[QT][S_];
  __shared__ float qs[QT][D_];
  // Support bitmap: bit b of kmask[q][g] == 4-key block (g*32+b) has p>0
  // for query q. Built by phase 3 ballots; phase 4 iterates set bits only
  // (entmax support is ~10-30/2048 keys -> the old full p-scan was ~30us of
  // 4-way-bank-conflicted ds_read_b128 spent summing zeros).
  __shared__ unsigned int kmask[QT][16];

  const int t   = threadIdx.x;
  const int blk = blockIdx.x;
  const int bh  = blk >> 9;          // blk / (S_/QT)
  const int qt  = blk & 511;         // blk % (S_/QT)
  const size_t qoff = ((size_t)bh * S_ + (size_t)qt * QT) * D_;
  const float* qp = q + qoff;
  const float* kp = k + (size_t)bh * S_ * D_;
  const float* vp = v + (size_t)bh * S_ * D_;
  float* op = out + qoff;

  // ---- load q tile; fold scale (1/8) and the entmax /2 => *1/16
  ((float*)qs)[t] = qp[t] * 0.0625f;   // QT*D_ == BLOCK
  __syncthreads();

  // ---- phase 1: scores (pre-divided by 2). Thread t handles keys t+256*j.
  for (int j = 0; j < KPT; ++j) {
    const float* krow = kp + (size_t)(t + BLOCK * j) * D_;
    float a0 = 0.f, a1 = 0.f, a2 = 0.f, a3 = 0.f;
    // unroll 4 (not 16): full unroll hoisted ~320 values -> VGPR blowup in R1
#pragma unroll 4
    for (int dc = 0; dc < D_; dc += 4) {
      float4 kv = *(const float4*)(krow + dc);
      float4 q0 = *(const float4*)&qs[0][dc];
      float4 q1 = *(const float4*)&qs[1][dc];
      float4 q2 = *(const float4*)&qs[2][dc];
      float4 q3 = *(const float4*)&qs[3][dc];
      a0 = fmaf(q0.x, kv.x, a0); a0 = fmaf(q0.y, kv.y, a0);
      a0 = fmaf(q0.z, kv.z, a0); a0 = fmaf(q0.w, kv.w, a0);
      a1 = fmaf(q1.x, kv.x, a1); a1 = fmaf(q1.y, kv.y, a1);
      a1 = fmaf(q1.z, kv.z, a1); a1 = fmaf(q1.w, kv.w, a1);
      a2 = fmaf(q2.x, kv.x, a2); a2 = fmaf(q2.y, kv.y, a2);
      a2 = fmaf(q2.z, kv.z, a2); a2 = fmaf(q2.w, kv.w, a2);
      a3 = fmaf(q3.x, kv.x, a3); a3 = fmaf(q3.y, kv.y, a3);
      a3 = fmaf(q3.z, kv.z, a3); a3 = fmaf(q3.w, kv.w, a3);
    }
    const int kk = t + BLOCK * j;   // stride-1 across lanes: conflict-free
    sc[0][kk] = a0; sc[1][kk] = a1; sc[2][kk] = a2; sc[3][kk] = a3;
  }
  __syncthreads();

  // ---- phase 2/3: one wave per query. Row max + Newton for tau, then p.
  {
    const int wave = t >> 6;        // query index 0..3
    const int lane = t & 63;
    // row cache: 8 float4 = 32 VGPRs, live set here ~45 regs total
    float4 xv[8];
#pragma unroll
    for (int i = 0; i < 8; ++i)
      xv[i] = *(const float4*)&sc[wave][lane * 4 + i * 256];

    float m = -1e30f;
#pragma unroll
    for (int i = 0; i < 8; ++i) {
      m = fmaxf(m, fmaxf(fmaxf(xv[i].x, xv[i].y), fmaxf(xv[i].z, xv[i].w)));
    }
#pragma unroll
    for (int off = 32; off >= 1; off >>= 1)
      m = fmaxf(m, __shfl_xor(m, off, 64));
#pragma unroll
    for (int i = 0; i < 8; ++i) {   // x = (z - max(z))/2, max now 0
      xv[i].x -= m; xv[i].y -= m; xv[i].z -= m; xv[i].w -= m;
    }

    // Newton on f(tau) = sum max(x - tau, 0)^2 - 1, from tau = -1 (monotone
    // from below; S1 >= sqrt(S2) -> ~>=1 near the root, so no div-by-0).
    // Convexity guarantees |tau* - tau| <= step, so step < 1e-7 == converged.
    // Early exit is wave-uniform (tau identical across lanes post-butterfly).
    float tau = -1.0f;
    for (int it = 0; it < NEWTON_ITERS; ++it) {
      float s1 = 0.f, s2 = 0.f;
#pragma unroll
      for (int i = 0; i < 8; ++i) {
        float u0 = fmaxf(xv[i].x - tau, 0.f);
        float u1 = fmaxf(xv[i].y - tau, 0.f);
        float u2 = fmaxf(xv[i].z - tau, 0.f);
        float u3 = fmaxf(xv[i].w - tau, 0.f);
        s1 += (u0 + u1) + (u2 + u3);
        s2 = fmaf(u0, u0, s2); s2 = fmaf(u1, u1, s2);
        s2 = fmaf(u2, u2, s2); s2 = fmaf(u3, u3, s2);
      }
#pragma unroll
      for (int off = 32; off >= 1; off >>= 1) {
        s1 += __shfl_xor(s1, off, 64);
        s2 += __shfl_xor(s2, off, 64);
      }
      float step = (s2 - 1.0f) / (2.0f * s1);
      tau += step;
      if (step < 1e-7f) break;      // typ. converges in ~6-10 iters
    }

    // p = clip(x - tau, 0)^2, write back over scores; ballot support bitmap.
#pragma unroll
    for (int i = 0; i < 8; ++i) {
      float u0 = fmaxf(xv[i].x - tau, 0.f);
      float u1 = fmaxf(xv[i].y - tau, 0.f);
      float u2 = fmaxf(xv[i].z - tau, 0.f);
      float u3 = fmaxf(xv[i].w - tau, 0.f);
      float4 r; r.x = u0*u0; r.y = u1*u1; r.z = u2*u2; r.w = u3*u3;
      *(float4*)&sc[wave][lane * 4 + i * 256] = r;
      // 4-key block index = lane + i*64 -> word 2i+(lane>>5), bit lane&31.
      unsigned long long act = __ballot(((u0 + u1) + (u2 + u3)) > 0.f);
      if (lane == 0) {
        kmask[wave][2 * i]     = (unsigned int)act;
        kmask[wave][2 * i + 1] = (unsigned int)(act >> 32);
      }
    }
  }
  __syncthreads();

  // ---- phase 4: out = p @ v over ACTIVE key-blocks only.
  // 16 key-groups x 16 dim-lanes (float4 dims); thread g owns keys
  // [g*128, g*128+128) == exactly mask word g (32 4-key blocks).
  {
    const int d4 = t & 15;          // float4 column within D
    const int g  = t >> 4;          // key group, 128 keys each
    const float4* v4 = (const float4*)vp;
    float4 acc0 = {0,0,0,0}, acc1 = {0,0,0,0}, acc2 = {0,0,0,0}, acc3 = {0,0,0,0};
    const int k0 = g * 128;
    unsigned int mrem = kmask[0][g] | kmask[1][g] | kmask[2][g] | kmask[3][g];
    while (mrem) {
      const int b = __ffs(mrem) - 1;
      mrem &= mrem - 1;
      const int kk = k0 + b * 4;
      float4 p0 = *(const float4*)&sc[0][kk];
      float4 p1 = *(const float4*)&sc[1][kk];
      float4 p2 = *(const float4*)&sc[2][kk];
      float4 p3 = *(const float4*)&sc[3][kk];
#pragma unroll
      for (int u = 0; u < 4; ++u) {
        float4 vv = v4[(size_t)(kk + u) * (D_ / 4) + d4];
        float c0 = comp(p0, u), c1 = comp(p1, u), c2 = comp(p2, u), c3 = comp(p3, u);
        acc0.x = fmaf(c0, vv.x, acc0.x); acc0.y = fmaf(c0, vv.y, acc0.y);
        acc0.z = fmaf(c0, vv.z, acc0.z); acc0.w = fmaf(c0, vv.w, acc0.w);
        acc1.x = fmaf(c1, vv.x, acc1.x); acc1.y = fmaf(c1, vv.y, acc1.y);
        acc1.z = fmaf(c1, vv.z, acc1.z); acc1.w = fmaf(c1, vv.w, acc1.w);
        acc2.x = fmaf(c2, vv.x, acc2.x); acc2.y = fmaf(c2, vv.y, acc2.y);
        acc2.z = fmaf(c2, vv.z, acc2.z); acc2.w = fmaf(c2, vv.w, acc2.w);
        acc3.x = fmaf(c3, vv.x, acc3.x); acc3.y = fmaf(c3, vv.y, acc3.y);
        acc3.z = fmaf(c3, vv.z, acc3.z); acc3.w = fmaf(c3, vv.w, acc3.w);
      }
    }
    __syncthreads();                 // all p reads done; safe to overwrite sc
    float* red = &sc[0][0];          // red[g][qq][d] : 16*4*64 floats = 16KB
    *(float4*)&red[(g * QT + 0) * D_ + d4 * 4] = acc0;
    *(float4*)&red[(g * QT + 1) * D_ + d4 * 4] = acc1;
    *(float4*)&red[(g * QT + 2) * D_ + d4 * 4] = acc2;
    *(float4*)&red[(g * QT + 3) * D_ + d4 * 4] = acc3;
    __syncthreads();
    // final cross-group reduction: thread -> (qq, d)
    const int qq = t >> 6, d = t & 63;
    float sum = 0.f;
#pragma unroll
    for (int gg = 0; gg < 16; ++gg) sum += red[(gg * QT + qq) * D_ + d];
    op[qq * D_ + d] = sum;
  }
}

extern "C" void kernel_launch(void* const* d_in, const int* in_sizes, int n_in,
                              void* d_out, int out_size, void* d_ws, size_t ws_size,
                              hipStream_t stream) {
  const float* q = (const float*)d_in[0];
  const float* k = (const float*)d_in[1];
  const float* v = (const float*)d_in[2];
  float* out = (float*)d_out;
  dim3 grid(BH_ * (S_ / QT));   // 16 * 512 = 8192 blocks
  entmax_attn_kernel<<<grid, dim3(BLOCK), 0, stream>>>(q, k, v, out);
}

// Round 2
// 366.331 us; speedup vs baseline: 1.6165x; 1.4997x over previous
//
#include <hip/hip_runtime.h>
#include <math.h>

// Problem constants (B=2, H=8, S=2048, D=64)
#define BH_    16          // B*H
#define S_     2048
#define D_     64
#define QT     16          // queries per block == MFMA M
#define BLOCK  1024        // 16 waves
#define NW     16
#define KTW    8           // 16x16 C-tiles per wave: 8*16 = 128 keys/wave
#define CAP    384         // per-query compacted support capacity (~20 typ.)
#define MAXIT  24

typedef __attribute__((ext_vector_type(8))) short bf16x8;   // 8 bf16 = 4 VGPR
typedef __attribute__((ext_vector_type(4))) float f32x4;

// Exact hi/lo bf16 truncation split of 8 consecutive floats.
// x = hi + lo + eps, |eps| <= 2^-15 |x|; products use hh + hl + lh (drop ll).
// Element i of the frag <-> d = base + i; A and B frags use the SAME
// convention, so the result is layout-permutation-proof.
__device__ __forceinline__ void split8(const float4 f0, const float4 f1,
                                       bf16x8& hi, bf16x8& lo) {
  union { bf16x8 v; unsigned int u[4]; } H, L;
  const float ff[8] = {f0.x, f0.y, f0.z, f0.w, f1.x, f1.y, f1.z, f1.w};
#pragma unroll
  for (int p = 0; p < 4; ++p) {
    unsigned int b0 = __float_as_uint(ff[2 * p]);
    unsigned int b1 = __float_as_uint(ff[2 * p + 1]);
    unsigned int h0 = b0 & 0xFFFF0000u;
    unsigned int h1 = b1 & 0xFFFF0000u;
    H.u[p] = (h0 >> 16) | h1;                       // lo short = elem 2p
    float l0 = ff[2 * p]     - __uint_as_float(h0); // exact in fp32
    float l1 = ff[2 * p + 1] - __uint_as_float(h1);
    L.u[p] = (__float_as_uint(l0) >> 16) | (__float_as_uint(l1) & 0xFFFF0000u);
  }
  hi = H.v; lo = L.v;
}

__global__ __launch_bounds__(BLOCK, 4)   // cap VGPR at 128; 1 block/CU
void entmax_attn_kernel(const float* __restrict__ q,
                        const float* __restrict__ k,
                        const float* __restrict__ v,
                        float* __restrict__ out) {
  __shared__ float redS1[NW][QT];      // per-wave per-row partials
  __shared__ float redS2[NW][QT];
  __shared__ float stepb[QT];          // published rowmax / Newton step
  __shared__ int   flags[MAXIT];       // per-iter "not converged" flags
  __shared__ unsigned int cnt[QT];
  __shared__ int   lidx[QT][CAP];      // compacted support: key indices
  __shared__ float lval[QT][CAP];      // compacted support: p (fp32!)

  const int t    = threadIdx.x;
  const int wid  = t >> 6;             // 0..15
  const int lane = t & 63;
  const int g    = lane >> 4;          // 0..3 lane group
  const int col  = lane & 15;          // MFMA row/col index

  const int bh = blockIdx.x >> 7;      // 16 heads
  const int qt = blockIdx.x & 127;     // 128 q-tiles of 16
  const float* qp = q + ((size_t)bh * S_ + (size_t)qt * QT) * D_;
  const float* kp = k + (size_t)bh * S_ * D_;
  const float* vp = v + (size_t)bh * S_ * D_;
  float* op = out + ((size_t)bh * S_ + (size_t)qt * QT) * D_;

  if (t < MAXIT) flags[t] = 0;
  if (t < QT)    cnt[t]   = 0;

  // ---- Q fragments (identical in all waves): A row m = col, d = ks*32+g*8+i.
  // Fold scale (1/8) and entmax /2 => *1/16 (power of 2: exact prescale).
  bf16x8 qh[2], ql[2];
#pragma unroll
  for (int ks = 0; ks < 2; ++ks) {
    const float* src = qp + col * D_ + ks * 32 + g * 8;
    float4 f0 = *(const float4*)src;
    float4 f1 = *(const float4*)(src + 4);
    f0.x *= 0.0625f; f0.y *= 0.0625f; f0.z *= 0.0625f; f0.w *= 0.0625f;
    f1.x *= 0.0625f; f1.y *= 0.0625f; f1.z *= 0.0625f; f1.w *= 0.0625f;
    split8(f0, f1, qh[ks], ql[ks]);
  }

  // ---- QK^T: wave wid owns keys [wid*128, wid*128+128), 8 C-tiles.
  // acc[kt][j] = x[row = g*4+j][key = wid*128 + kt*16 + col]  (verified C map)
  f32x4 acc[KTW];
  const f32x4 zero4 = {0.f, 0.f, 0.f, 0.f};
#pragma unroll
  for (int kt = 0; kt < KTW; ++kt) {
    acc[kt] = zero4;
    const float* krow = kp + (size_t)(wid * 128 + kt * 16 + col) * D_;
#pragma unroll
    for (int ks = 0; ks < 2; ++ks) {
      bf16x8 kh, kl;
      const float* src = krow + ks * 32 + g * 8;
      split8(*(const float4*)src, *(const float4*)(src + 4), kh, kl);
      acc[kt] = __builtin_amdgcn_mfma_f32_16x16x32_bf16(qh[ks], kh, acc[kt], 0, 0, 0);
      acc[kt] = __builtin_amdgcn_mfma_f32_16x16x32_bf16(qh[ks], kl, acc[kt], 0, 0, 0);
      acc[kt] = __builtin_amdgcn_mfma_f32_16x16x32_bf16(ql[ks], kh, acc[kt], 0, 0, 0);
    }
  }

  // ---- row max (never subtracted from acc; folded into c = m + tau)
  float m[4];
#pragma unroll
  for (int j = 0; j < 4; ++j) {
    float mm = acc[0][j];
#pragma unroll
    for (int kt = 1; kt < KTW; ++kt) mm = fmaxf(mm, acc[kt][j]);
    m[j] = mm;
  }
#pragma unroll
  for (int off = 1; off < 16; off <<= 1) {
#pragma unroll
    for (int j = 0; j < 4; ++j) m[j] = fmaxf(m[j], __shfl_xor(m[j], off, 64));
  }
  if (col == 0) {
#pragma unroll
    for (int j = 0; j < 4; ++j) redS1[wid][g * 4 + j] = m[j];
  }
  __syncthreads();
  if (t < QT) {                         // wave0: cross-wave max per row
    float mm = redS1[0][t];
#pragma unroll
    for (int w = 1; w < NW; ++w) mm = fmaxf(mm, redS1[w][t]);
    stepb[t] = mm;
  }
  __syncthreads();
#pragma unroll
  for (int j = 0; j < 4; ++j) m[j] = stepb[g * 4 + j];

  // ---- Newton on f(tau) = sum (x - m - tau)_+^2 - 1 from tau = -1
  // (convex, monotone from below; S1 >= 1 before convergence).
  float tau[4] = {-1.f, -1.f, -1.f, -1.f};
  for (int it = 0; it < MAXIT; ++it) {
    float s1[4] = {0, 0, 0, 0}, s2[4] = {0, 0, 0, 0};
    float c[4];
#pragma unroll
    for (int j = 0; j < 4; ++j) c[j] = m[j] + tau[j];
#pragma unroll
    for (int kt = 0; kt < KTW; ++kt) {
#pragma unroll
      for (int j = 0; j < 4; ++j) {
        float u = fmaxf(acc[kt][j] - c[j], 0.f);
        s1[j] += u; s2[j] = fmaf(u, u, s2[j]);
      }
    }
#pragma unroll
    for (int off = 1; off < 16; off <<= 1) {
#pragma unroll
      for (int j = 0; j < 4; ++j) {
        s1[j] += __shfl_xor(s1[j], off, 64);
        s2[j] += __shfl_xor(s2[j], off, 64);
      }
    }
    if (col == 0) {
#pragma unroll
      for (int j = 0; j < 4; ++j) {
        redS1[wid][g * 4 + j] = s1[j];
        redS2[wid][g * 4 + j] = s2[j];
      }
    }
    __syncthreads();
    if (t < QT) {                        // wave0: totals + step per row
      float S1 = 0.f, S2 = 0.f;
#pragma unroll
      for (int w = 0; w < NW; ++w) { S1 += redS1[w][t]; S2 += redS2[w][t]; }
      float step = (S2 - 1.0f) / (2.0f * S1);
      stepb[t] = step;
      if (step > 1e-6f) atomicOr(&flags[it], 1);
    }
    __syncthreads();
#pragma unroll
    for (int j = 0; j < 4; ++j) tau[j] += stepb[g * 4 + j];
    if (!flags[it]) break;               // block-uniform exit
  }

  // ---- p = (x - m - tau)_+^2 ; compact nonzeros into per-query LDS lists.
  // Support ~10-30/2048 for N(0,1) scores; CAP=384 is ~15-25x margin.
#pragma unroll
  for (int kt = 0; kt < KTW; ++kt) {
#pragma unroll
    for (int j = 0; j < 4; ++j) {
      float u = fmaxf(acc[kt][j] - (m[j] + tau[j]), 0.f);
      if (u > 0.f) {
        const int row = g * 4 + j;
        unsigned int s = atomicAdd(&cnt[row], 1u);
        if (s < CAP) {
          lidx[row][s] = wid * 128 + kt * 16 + col;
          lval[row][s] = u * u;
        }
      }
    }
  }
  __syncthreads();

  // ---- PV from the compacted list: thread (q = wid, d = lane).
  // p broadcast from LDS, V rows fp32 from L2 (coalesced 256B per key).
  {
    const int qq = wid;
    const int d  = lane;
    int n = (int)cnt[qq]; if (n > CAP) n = CAP;
    float s = 0.f;
    for (int i = 0; i < n; ++i) {
      s = fmaf(lval[qq][i], vp[(size_t)lidx[qq][i] * D_ + d], s);
    }
    op[qq * D_ + d] = s;
  }
}

extern "C" void kernel_launch(void* const* d_in, const int* in_sizes, int n_in,
                              void* d_out, int out_size, void* d_ws, size_t ws_size,
                              hipStream_t stream) {
  const float* q = (const float*)d_in[0];
  const float* k = (const float*)d_in[1];
  const float* v = (const float*)d_in[2];
  float* out = (float*)d_out;
  dim3 grid(BH_ * (S_ / QT));   // 16 * 128 = 2048 blocks
  entmax_attn_kernel<<<grid, dim3(BLOCK), 0, stream>>>(q, k, v, out);
}